// Round 11
// baseline (251.868 us; speedup 1.0000x reference)
//
#include <hip/hip_runtime.h>

#define NL 128          // N_LABELS
#define TT 512          // T
#define NB 512          // B
#define START_IDX 126
#define STOP_IDX 127

typedef __attribute__((ext_vector_type(8))) short bf16x8;
typedef __attribute__((ext_vector_type(4))) float f32x4;
typedef __attribute__((ext_vector_type(4))) unsigned u32x4;

__device__ __forceinline__ short f2bf(float x) {
    union { float f; unsigned u; } v; v.f = x;
    unsigned r = (v.u + 0x7FFFu + ((v.u >> 16) & 1u)) >> 16;  // RNE
    return (short)r;
}

__device__ __forceinline__ unsigned cvt_pk_bf16(float lo, float hi) {
    unsigned r;
    asm("v_cvt_pk_bf16_f32 %0, %1, %2" : "=v"(r) : "v"(lo), "v"(hi));
    return r;   // low half <- lo, high half <- hi
}

// LDS-only barrier: drain LDS ops (ds_write visibility) but NOT vmcnt — the
// in-flight global logits prefetches are lane-private and span barriers.
#define BAR() do {                                                            \
    asm volatile("s_waitcnt lgkmcnt(0)" ::: "memory");                        \
    __builtin_amdgcn_s_barrier();                                             \
} while (0)

#define MFMA16(A_, B_, C_) __builtin_amdgcn_mfma_f32_16x16x32_bf16(A_, B_, C_, 0, 0, 0)

// ---------------------------------------------------------------------------
// R11: TWO independent 16-batch pipelines (A,B) per block, one barrier/round.
// Per pipeline (same as R10): 16 batches in MFMA columns; 4 waves; wave w owns
// m-tiles {w, w+4} = B-word-group kk=w via the phi twist; exchange =
// 1 ds_write_b128 + 3 ds_read_b128 per step; el pipeline 4 raw + 2 exp slots
// (issue at t for t+3, exp 2 rounds after issue -> HBM latency covered).
// B's MFMA/VALU fills A's exchange stalls and vice versa; the barrier cost is
// amortized over two t-advances. afr (exp(trans) fragments) shared.
// Lag-1 cross-wave max (pub t%4==2, cons t%4==3) -> exact 2^k rescale.
// Per-batch freeze at t==lenc via keep-old cndmask.
// ---------------------------------------------------------------------------
#define STEP_PRE(P, PI_, T_, PUB_, CONS_, EU_, EB_, RS_, RD_) do {            \
    u32x4 bo_ = {P##_bw0, P##_bw1, P##_bw2, P##_bw3};                         \
    bf16x8 bO_ = __builtin_bit_cast(bf16x8, bo_);                             \
    bf16x8 bA_ = __builtin_bit_cast(bf16x8, P##_bvA);                         \
    bf16x8 bB_ = __builtin_bit_cast(bf16x8, P##_bvB);                         \
    bf16x8 bC_ = __builtin_bit_cast(bf16x8, P##_bvC);                         \
    f32x4 a0_ = {0.f,0.f,0.f,0.f}, a1_ = {0.f,0.f,0.f,0.f};                   \
    a0_ = MFMA16(afr[0][0], bO_, a0_);  a1_ = MFMA16(afr[1][0], bO_, a1_);    \
    a0_ = MFMA16(afr[0][1], bA_, a0_);  a1_ = MFMA16(afr[1][1], bA_, a1_);    \
    a0_ = MFMA16(afr[0][2], bB_, a0_);  a1_ = MFMA16(afr[1][2], bB_, a1_);    \
    a0_ = MFMA16(afr[0][3], bC_, a0_);  a1_ = MFMA16(afr[1][3], bC_, a1_);    \
    { int tp_ = (T_) + 3; if (tp_ > TT - 1) tp_ = TT - 1;                     \
      const float* lp_ = P##_lsrc + (size_t)tp_ * NL;                         \
      P##_##RD_##X = *(const f32x4*)(lp_ + eo0);                              \
      P##_##RD_##Y = *(const f32x4*)(lp_ + eo1); }                            \
    _Pragma("unroll")                                                         \
    for (int r_ = 0; r_ < 4; ++r_) {                                          \
        P##_##EB_##X[r_] = __expf(P##_##RS_##X[r_]);                          \
        P##_##EB_##Y[r_] = __expf(P##_##RS_##Y[r_]);                          \
    }                                                                         \
    float nv0_[4], nv1_[4];                                                   \
    _Pragma("unroll")                                                         \
    for (int r_ = 0; r_ < 4; ++r_) {                                          \
        nv0_[r_] = a0_[r_] * P##_##EU_##X[r_];                                \
        nv1_[r_] = a1_[r_] * P##_##EU_##Y[r_];                                \
    }                                                                         \
    const bool live_ = (T_) < P##_lenc;                                       \
    if (CONS_) {                                                              \
        float mx_ = fmaxf(fmaxf(sm##P[0][c], sm##P[1][c]),                    \
                          fmaxf(sm##P[2][c], sm##P[3][c]));                   \
        const unsigned eb_ = (__float_as_uint(mx_) >> 23) & 0xFFu;            \
        const float sc_ = __uint_as_float(((253u - eb_) & 0xFFu) << 23);      \
        _Pragma("unroll")                                                     \
        for (int r_ = 0; r_ < 4; ++r_) { nv0_[r_] *= sc_; nv1_[r_] *= sc_; }  \
        if (live_) P##_cbi += (int)eb_ - 126;                                 \
    }                                                                         \
    if (PUB_) {                                                               \
        float lm_ = fmaxf(fmaxf(fmaxf(nv0_[0], nv0_[1]), fmaxf(nv0_[2], nv0_[3])), \
                          fmaxf(fmaxf(nv1_[0], nv1_[1]), fmaxf(nv1_[2], nv1_[3]))); \
        lm_ = fmaxf(lm_, __shfl_xor(lm_, 16));                                \
        lm_ = fmaxf(lm_, __shfl_xor(lm_, 32));                                \
        if (g == 0) sm##P[w][c] = lm_;                                        \
    }                                                                         \
    { const unsigned n0_ = cvt_pk_bf16(nv0_[0], nv0_[1]);                     \
      const unsigned n1_ = cvt_pk_bf16(nv0_[2], nv0_[3]);                     \
      const unsigned n2_ = cvt_pk_bf16(nv1_[0], nv1_[1]);                     \
      const unsigned n3_ = cvt_pk_bf16(nv1_[2], nv1_[3]);                     \
      P##_bw0 = live_ ? n0_ : P##_bw0;  P##_bw1 = live_ ? n1_ : P##_bw1;      \
      P##_bw2 = live_ ? n2_ : P##_bw2;  P##_bw3 = live_ ? n3_ : P##_bw3; }    \
    { u32x4 wv_ = {P##_bw0, P##_bw1, P##_bw2, P##_bw3};                       \
      *(u32x4*)(&sb[PI_][((T_) + 1) & 1][0] + w * 1280 + slotOff) = wv_; }    \
} while (0)

#define STEP_POST(P, PI_, T_) do {                                            \
    const char* nb_ = &sb[PI_][((T_) + 1) & 1][0];                            \
    P##_bvA = *(const u32x4*)(nb_ + kA + slotOff);                            \
    P##_bvB = *(const u32x4*)(nb_ + kB + slotOff);                            \
    P##_bvC = *(const u32x4*)(nb_ + kC + slotOff);                            \
} while (0)

#define ROUND(T_, PUB_, CONS_, EU_, EB_, RS_, RD_) do {                       \
    STEP_PRE(A, 0, T_, PUB_, CONS_, EU_, EB_, RS_, RD_);                      \
    STEP_PRE(B, 1, T_, PUB_, CONS_, EU_, EB_, RS_, RD_);                      \
    BAR();                                                                    \
    STEP_POST(A, 0, T_);                                                      \
    STEP_POST(B, 1, T_);                                                      \
} while (0)

#define EPILOG(P, BB_) do {                                                   \
    float s = 0.f;                                                            \
    const float* stopr = trans + STOP_IDX * NL + 4 * g;                       \
    _Pragma("unroll")                                                         \
    for (int pos = 0; pos < 4; ++pos) {                                       \
        const int kk = (w + pos) & 3;                                         \
        u32x4 gv;                                                             \
        if (pos == 0)      gv = (u32x4){P##_bw0, P##_bw1, P##_bw2, P##_bw3};  \
        else if (pos == 1) gv = P##_bvA;                                      \
        else if (pos == 2) gv = P##_bvB;                                      \
        else               gv = P##_bvC;                                      \
        f32x4 t0 = *(const f32x4*)(stopr + kk * 16);                          \
        f32x4 t1 = *(const f32x4*)(stopr + (kk + 4) * 16);                    \
        _Pragma("unroll")                                                     \
        for (int i = 0; i < 2; ++i) {                                         \
            const unsigned wd = gv[i];                                        \
            s += __uint_as_float(wd << 16)         * __expf(t0[2 * i]);       \
            s += __uint_as_float(wd & 0xFFFF0000u) * __expf(t0[2 * i + 1]);   \
        }                                                                     \
        _Pragma("unroll")                                                     \
        for (int i = 2; i < 4; ++i) {                                         \
            const unsigned wd = gv[i];                                        \
            s += __uint_as_float(wd << 16)         * __expf(t1[2 * (i - 2)]); \
            s += __uint_as_float(wd & 0xFFFF0000u) * __expf(t1[2 * (i - 2) + 1]); \
        }                                                                     \
    }                                                                         \
    s += __shfl_xor(s, 16);                                                   \
    s += __shfl_xor(s, 32);                                                   \
    if (g == 0)                                                               \
        out[(BB_) + c] = (float)P##_cbi * 0.69314718055994531f + __logf(s);   \
} while (0)

__global__ __launch_bounds__(256, 1)
void crf_scan(const float* __restrict__ logits,
              const int* __restrict__ lens,
              const float* __restrict__ trans,
              float* __restrict__ out)
{
    const int b0A  = blockIdx.x * 32;
    const int b0B  = b0A + 16;
    const int tid  = threadIdx.x;
    const int w    = tid >> 6;           // wave: owns m-tiles {w, w+4} = group kk=w
    const int lane = tid & 63;
    const int c    = lane & 15;          // batch / A row within tile / C col
    const int g    = lane >> 4;          // k-group

    // [pipe][buf][ kk*1280 + c*80 + g*16 ] (stride 80 -> conflict-light b128)
    __shared__ __align__(16) char sb[2][2][4 * 16 * 80];
    __shared__ float smA[4][16];
    __shared__ float smB[4][16];

    // ---- A fragments (shared by both pipelines), chain-ordered ----
    bf16x8 afr[2][4];
    #pragma unroll
    for (int mi = 0; mi < 2; ++mi) {
        const int M = w + 4 * mi;
        const float* rowp = trans + (M * 16 + c) * NL + 4 * g;
        #pragma unroll
        for (int pos = 0; pos < 4; ++pos) {
            const int kk = (w + pos) & 3;
            f32x4 lo4 = *(const f32x4*)(rowp + kk * 16);        // e=0..3
            f32x4 hi4 = *(const f32x4*)(rowp + (kk + 4) * 16);  // e=4..7
            bf16x8 a;
            #pragma unroll
            for (int j = 0; j < 4; ++j) {
                a[j]     = f2bf(__expf(lo4[j]));
                a[j + 4] = f2bf(__expf(hi4[j]));
            }
            afr[mi][pos] = a;
        }
    }

    int A_lenc = lens[b0A + c];
    A_lenc = A_lenc < 1 ? 1 : (A_lenc > TT ? TT : A_lenc);
    int B_lenc = lens[b0B + c];
    B_lenc = B_lenc < 1 ? 1 : (B_lenc > TT ? TT : B_lenc);
    int gl = A_lenc > B_lenc ? A_lenc : B_lenc;
    #pragma unroll
    for (int d = 1; d < 16; d <<= 1) { int o = __shfl_xor(gl, d); gl = gl > o ? gl : o; }
    const int glen = __builtin_amdgcn_readfirstlane(gl);

    const int slotOff = c * 80 + g * 16;
    const int kA = ((w + 1) & 3) * 1280;
    const int kB = ((w + 2) & 3) * 1280;
    const int kC = ((w + 3) & 3) * 1280;

    // ---- init: v0 one-hot at START(126) -> group kk=3, g=3, word 3, low half
    unsigned A_bw0 = 0u, A_bw1 = 0u, A_bw2 = 0u,
             A_bw3 = (w == 3 && g == 3) ? 0x00003F80u : 0u;
    unsigned B_bw0 = 0u, B_bw1 = 0u, B_bw2 = 0u, B_bw3 = A_bw3;
    { u32x4 z = {A_bw0, A_bw1, A_bw2, A_bw3};
      *(u32x4*)(&sb[0][0][0] + w * 1280 + slotOff) = z;
      *(u32x4*)(&sb[1][0][0] + w * 1280 + slotOff) = z; }
    BAR();
    u32x4 A_bvA = *(const u32x4*)(&sb[0][0][0] + kA + slotOff);
    u32x4 A_bvB = *(const u32x4*)(&sb[0][0][0] + kB + slotOff);
    u32x4 A_bvC = *(const u32x4*)(&sb[0][0][0] + kC + slotOff);
    u32x4 B_bvA = *(const u32x4*)(&sb[1][0][0] + kA + slotOff);
    u32x4 B_bvB = *(const u32x4*)(&sb[1][0][0] + kB + slotOff);
    u32x4 B_bvC = *(const u32x4*)(&sb[1][0][0] + kC + slotOff);

    const float* A_lsrc = logits + (size_t)(b0A + c) * TT * NL;
    const float* B_lsrc = logits + (size_t)(b0B + c) * TT * NL;
    const int eo0 = w * 16 + 4 * g;          // labels of m-tile w
    const int eo1 = (w + 4) * 16 + 4 * g;    // labels of m-tile w+4

    // ---- el pipelines: 4 rotating raw pairs + 2 exp pairs, per pipeline ----
    f32x4 A_R0X, A_R0Y, A_R1X, A_R1Y, A_R2X, A_R2Y, A_R3X, A_R3Y;
    f32x4 A_E0X, A_E0Y, A_E1X, A_E1Y;
    f32x4 B_R0X, B_R0Y, B_R1X, B_R1Y, B_R2X, B_R2Y, B_R3X, B_R3Y;
    f32x4 B_E0X, B_E0Y, B_E1X, B_E1Y;
    A_R0X = *(const f32x4*)(A_lsrc + eo0);          A_R0Y = *(const f32x4*)(A_lsrc + eo1);
    A_R1X = *(const f32x4*)(A_lsrc + NL + eo0);     A_R1Y = *(const f32x4*)(A_lsrc + NL + eo1);
    A_R2X = *(const f32x4*)(A_lsrc + 2 * NL + eo0); A_R2Y = *(const f32x4*)(A_lsrc + 2 * NL + eo1);
    B_R0X = *(const f32x4*)(B_lsrc + eo0);          B_R0Y = *(const f32x4*)(B_lsrc + eo1);
    B_R1X = *(const f32x4*)(B_lsrc + NL + eo0);     B_R1Y = *(const f32x4*)(B_lsrc + NL + eo1);
    B_R2X = *(const f32x4*)(B_lsrc + 2 * NL + eo0); B_R2Y = *(const f32x4*)(B_lsrc + 2 * NL + eo1);
    #pragma unroll
    for (int r = 0; r < 4; ++r) {
        A_E0X[r] = __expf(A_R0X[r]);  A_E0Y[r] = __expf(A_R0Y[r]);
        B_E0X[r] = __expf(B_R0X[r]);  B_E0Y[r] = __expf(B_R0Y[r]);
    }

    int A_cbi = 0, B_cbi = 0;
    int t = 0;
    const int tmain = glen & ~3;
    for (; t < tmain; t += 4) {
        ROUND(t + 0, false, false, E0, E1, R1, R3);
        ROUND(t + 1, false, false, E1, E0, R2, R0);
        ROUND(t + 2, true,  false, E0, E1, R3, R1);
        ROUND(t + 3, false, true,  E1, E0, R0, R2);
    }
    if (t < glen) { ROUND(t, false, false, E0, E1, R1, R3); ++t; }
    if (t < glen) { ROUND(t, false, false, E1, E0, R2, R0); ++t; }
    if (t < glen) { ROUND(t, true,  false, E0, E1, R3, R1); ++t; }

    // ---- epilogues: wave 0 -> pipeline A, wave 1 -> pipeline B ----
    if (w == 0)      EPILOG(A, b0A);
    else if (w == 1) EPILOG(B, b0B);
}

extern "C" void kernel_launch(void* const* d_in, const int* in_sizes, int n_in,
                              void* d_out, int out_size, void* d_ws, size_t ws_size,
                              hipStream_t stream) {
    const float* logits = (const float*)d_in[0];
    const int*   lens   = (const int*)d_in[1];
    const float* trans  = (const float*)d_in[2];
    float*       outp   = (float*)d_out;
    crf_scan<<<NB / 32, 256, 0, stream>>>(logits, lens, trans, outp);
}

// Round 12
// 202.292 us; speedup vs baseline: 1.2451x; 1.2451x over previous
//
#include <hip/hip_runtime.h>

#define NL 128          // N_LABELS
#define TT 512          // T
#define NB 512          // B
#define START_IDX 126
#define STOP_IDX 127

typedef __attribute__((ext_vector_type(8))) short bf16x8;
typedef __attribute__((ext_vector_type(4))) float f32x4;
typedef __attribute__((ext_vector_type(4))) unsigned u32x4;

__device__ __forceinline__ short f2bf(float x) {
    union { float f; unsigned u; } v; v.f = x;
    unsigned r = (v.u + 0x7FFFu + ((v.u >> 16) & 1u)) >> 16;  // RNE
    return (short)r;
}

__device__ __forceinline__ unsigned cvt_pk_bf16(float lo, float hi) {
    unsigned r;
    asm("v_cvt_pk_bf16_f32 %0, %1, %2" : "=v"(r) : "v"(lo), "v"(hi));
    return r;   // low half <- lo, high half <- hi
}

// LDS-only barrier: drain LDS ops (ds_write visibility) but NOT vmcnt — the
// in-flight global logits prefetches are lane-private and span barriers.
#define BAR() do {                                                            \
    asm volatile("s_waitcnt lgkmcnt(0)" ::: "memory");                        \
    __builtin_amdgcn_s_barrier();                                             \
} while (0)

#define MFMA16(A_, B_, C_) __builtin_amdgcn_mfma_f32_16x16x32_bf16(A_, B_, C_, 0, 0, 0)

// ---------------------------------------------------------------------------
// R12: TWO waves per block (16 batches in MFMA columns). Wave w owns m-tiles
// {w, w+2, w+4, w+6}; under phi(kk*32+8g+j) = (kk+4*(j>>2))*16+4g+(j&3) the
// pairs (w,w+4) and (w+2,w+6) yield B word-groups kk=w and kk=w+2 FULLY
// in-register. Exchange = 2 ds_write_b128 + 2 ds_read_b128 per step, one
// 2-wave LDS-only barrier; the 8 own-group MFMAs cover the read latency.
// el pipeline: 4 rotating raw quads + 2 exp quads (issue t+3, exp t+1 ahead
// -> ~2 steps of HBM-latency cover). Lag-1 cross-wave max (pub t%4==2, cons
// t%4==3) -> exact 2^k rescale. Per-batch freeze at t==lenc via keep-old.
// ---------------------------------------------------------------------------
#define STEP(T_, PUB_, CONS_, EU_, EB_, RS_, RD_) do {                        \
    u32x4 bp_ = {bwP0, bwP1, bwP2, bwP3};                                     \
    u32x4 bq_ = {bwQ0, bwQ1, bwQ2, bwQ3};                                     \
    bf16x8 bP_ = __builtin_bit_cast(bf16x8, bp_);                             \
    bf16x8 bQ_ = __builtin_bit_cast(bf16x8, bq_);                             \
    bf16x8 bX_ = __builtin_bit_cast(bf16x8, bvX);                             \
    bf16x8 bY_ = __builtin_bit_cast(bf16x8, bvY);                             \
    f32x4 a0_ = {0.f,0.f,0.f,0.f}, a1_ = {0.f,0.f,0.f,0.f};                   \
    f32x4 a2_ = {0.f,0.f,0.f,0.f}, a3_ = {0.f,0.f,0.f,0.f};                   \
    a0_ = MFMA16(afr[0][0], bP_, a0_);  a1_ = MFMA16(afr[1][0], bP_, a1_);    \
    a2_ = MFMA16(afr[2][0], bP_, a2_);  a3_ = MFMA16(afr[3][0], bP_, a3_);    \
    a0_ = MFMA16(afr[0][1], bQ_, a0_);  a1_ = MFMA16(afr[1][1], bQ_, a1_);    \
    a2_ = MFMA16(afr[2][1], bQ_, a2_);  a3_ = MFMA16(afr[3][1], bQ_, a3_);    \
    a0_ = MFMA16(afr[0][2], bX_, a0_);  a1_ = MFMA16(afr[1][2], bX_, a1_);    \
    a2_ = MFMA16(afr[2][2], bX_, a2_);  a3_ = MFMA16(afr[3][2], bX_, a3_);    \
    a0_ = MFMA16(afr[0][3], bY_, a0_);  a1_ = MFMA16(afr[1][3], bY_, a1_);    \
    a2_ = MFMA16(afr[2][3], bY_, a2_);  a3_ = MFMA16(afr[3][3], bY_, a3_);    \
    { int tp_ = (T_) + 3; if (tp_ > TT - 1) tp_ = TT - 1;                     \
      const float* lp_ = lsrc + (size_t)tp_ * NL;                             \
      RD_##A = *(const f32x4*)(lp_ + eoA);                                    \
      RD_##B = *(const f32x4*)(lp_ + eoB);                                    \
      RD_##C = *(const f32x4*)(lp_ + eoC);                                    \
      RD_##D = *(const f32x4*)(lp_ + eoD); }                                  \
    _Pragma("unroll")                                                         \
    for (int r_ = 0; r_ < 4; ++r_) {                                          \
        EB_##A[r_] = __expf(RS_##A[r_]);                                      \
        EB_##B[r_] = __expf(RS_##B[r_]);                                      \
        EB_##C[r_] = __expf(RS_##C[r_]);                                      \
        EB_##D[r_] = __expf(RS_##D[r_]);                                      \
    }                                                                         \
    float nv0_[4], nv1_[4], nv2_[4], nv3_[4];                                 \
    _Pragma("unroll")                                                         \
    for (int r_ = 0; r_ < 4; ++r_) {                                          \
        nv0_[r_] = a0_[r_] * EU_##A[r_];                                      \
        nv1_[r_] = a1_[r_] * EU_##B[r_];                                      \
        nv2_[r_] = a2_[r_] * EU_##C[r_];                                      \
        nv3_[r_] = a3_[r_] * EU_##D[r_];                                      \
    }                                                                         \
    const bool live_ = (T_) < lenc;                                           \
    if (CONS_) {                                                              \
        float mx_ = fmaxf(smax[0][c], smax[1][c]);                            \
        const unsigned eb_ = (__float_as_uint(mx_) >> 23) & 0xFFu;            \
        const float sc_ = __uint_as_float(((253u - eb_) & 0xFFu) << 23);      \
        _Pragma("unroll")                                                     \
        for (int r_ = 0; r_ < 4; ++r_) {                                      \
            nv0_[r_] *= sc_; nv1_[r_] *= sc_;                                 \
            nv2_[r_] *= sc_; nv3_[r_] *= sc_;                                 \
        }                                                                     \
        if (live_) cbi += (int)eb_ - 126;                                     \
    }                                                                         \
    if (PUB_) {                                                               \
        float lm_ = fmaxf(fmaxf(fmaxf(nv0_[0], nv0_[1]), fmaxf(nv0_[2], nv0_[3])), \
                          fmaxf(fmaxf(nv1_[0], nv1_[1]), fmaxf(nv1_[2], nv1_[3]))); \
        lm_ = fmaxf(lm_, fmaxf(fmaxf(nv2_[0], nv2_[1]), fmaxf(nv2_[2], nv2_[3]))); \
        lm_ = fmaxf(lm_, fmaxf(fmaxf(nv3_[0], nv3_[1]), fmaxf(nv3_[2], nv3_[3]))); \
        lm_ = fmaxf(lm_, __shfl_xor(lm_, 16));                                \
        lm_ = fmaxf(lm_, __shfl_xor(lm_, 32));                                \
        if (g == 0) smax[w][c] = lm_;                                         \
    }                                                                         \
    { const unsigned p0_ = cvt_pk_bf16(nv0_[0], nv0_[1]);                     \
      const unsigned p1_ = cvt_pk_bf16(nv0_[2], nv0_[3]);                     \
      const unsigned p2_ = cvt_pk_bf16(nv2_[0], nv2_[1]);                     \
      const unsigned p3_ = cvt_pk_bf16(nv2_[2], nv2_[3]);                     \
      const unsigned q0_ = cvt_pk_bf16(nv1_[0], nv1_[1]);                     \
      const unsigned q1_ = cvt_pk_bf16(nv1_[2], nv1_[3]);                     \
      const unsigned q2_ = cvt_pk_bf16(nv3_[0], nv3_[1]);                     \
      const unsigned q3_ = cvt_pk_bf16(nv3_[2], nv3_[3]);                     \
      bwP0 = live_ ? p0_ : bwP0;  bwP1 = live_ ? p1_ : bwP1;                  \
      bwP2 = live_ ? p2_ : bwP2;  bwP3 = live_ ? p3_ : bwP3;                  \
      bwQ0 = live_ ? q0_ : bwQ0;  bwQ1 = live_ ? q1_ : bwQ1;                  \
      bwQ2 = live_ ? q2_ : bwQ2;  bwQ3 = live_ ? q3_ : bwQ3; }                \
    char* nb_ = sb[((T_) + 1) & 1];                                           \
    { u32x4 wp_ = {bwP0, bwP1, bwP2, bwP3};                                   \
      u32x4 wq_ = {bwQ0, bwQ1, bwQ2, bwQ3};                                   \
      *(u32x4*)(nb_ + kP + slotOff) = wp_;                                    \
      *(u32x4*)(nb_ + kQ + slotOff) = wq_; }                                  \
    BAR();                                                                    \
    bvX = *(const u32x4*)(nb_ + kX + slotOff);                                \
    bvY = *(const u32x4*)(nb_ + kY + slotOff);                                \
} while (0)

__global__ __launch_bounds__(128, 1)
void crf_scan(const float* __restrict__ logits,
              const int* __restrict__ lens,
              const float* __restrict__ trans,
              float* __restrict__ out)
{
    const int b0   = blockIdx.x * 16;
    const int tid  = threadIdx.x;
    const int w    = tid >> 6;           // wave 0 or 1
    const int lane = tid & 63;
    const int c    = lane & 15;          // batch / A row within tile / C col
    const int g    = lane >> 4;          // k-group

    // slot(kk,c,g) = kk*1280 + c*80 + g*16 (stride 80 -> conflict-light b128)
    __shared__ __align__(16) char sb[2][4 * 16 * 80];
    __shared__ float smax[2][16];

    // ---- A fragments: afr[mi][pos], M(mi) = w + 2*mi,
    //      pos -> logical kk: {w, w+2, w+1, w+3} (own, own, read, read) ----
    const int kk0 = w;
    const int kk1 = (w + 2) & 3;
    const int kk2 = (w + 1) & 3;
    const int kk3 = (w + 3) & 3;
    bf16x8 afr[4][4];
    #pragma unroll
    for (int mi = 0; mi < 4; ++mi) {
        const int M = w + 2 * mi;
        const float* rowp = trans + (M * 16 + c) * NL + 4 * g;
        const int kks[4] = {kk0, kk1, kk2, kk3};
        #pragma unroll
        for (int pos = 0; pos < 4; ++pos) {
            const int kk = kks[pos];
            f32x4 lo4 = *(const f32x4*)(rowp + kk * 16);        // j=0..3
            f32x4 hi4 = *(const f32x4*)(rowp + (kk + 4) * 16);  // j=4..7
            bf16x8 a;
            #pragma unroll
            for (int j = 0; j < 4; ++j) {
                a[j]     = f2bf(__expf(lo4[j]));
                a[j + 4] = f2bf(__expf(hi4[j]));
            }
            afr[mi][pos] = a;
        }
    }

    int lenc = lens[b0 + c];
    lenc = lenc < 1 ? 1 : (lenc > TT ? TT : lenc);
    int gl = lenc;
    #pragma unroll
    for (int d = 1; d < 16; d <<= 1) { int o = __shfl_xor(gl, d); gl = gl > o ? gl : o; }
    const int glen = __builtin_amdgcn_readfirstlane(gl);

    const int slotOff = c * 80 + g * 16;
    const int kP = kk0 * 1280;
    const int kQ = kk1 * 1280;
    const int kX = kk2 * 1280;
    const int kY = kk3 * 1280;

    // ---- init: one-hot at START(126) -> group 3, word 3, low half, g==3.
    // Group 3 is wave 1's Q group ((1+2)&3 == 3).
    unsigned bwP0 = 0u, bwP1 = 0u, bwP2 = 0u, bwP3 = 0u;
    unsigned bwQ0 = 0u, bwQ1 = 0u, bwQ2 = 0u,
             bwQ3 = (w == 1 && g == 3) ? 0x00003F80u : 0u;
    { u32x4 zp = {bwP0, bwP1, bwP2, bwP3};
      u32x4 zq = {bwQ0, bwQ1, bwQ2, bwQ3};
      *(u32x4*)(sb[0] + kP + slotOff) = zp;
      *(u32x4*)(sb[0] + kQ + slotOff) = zq; }
    BAR();
    u32x4 bvX = *(const u32x4*)(sb[0] + kX + slotOff);
    u32x4 bvY = *(const u32x4*)(sb[0] + kY + slotOff);

    const float* lsrc = logits + (size_t)(b0 + c) * TT * NL;
    const int eoA = (w + 0) * 16 + 4 * g;    // labels of m-tile w
    const int eoB = (w + 2) * 16 + 4 * g;    // m-tile w+2
    const int eoC = (w + 4) * 16 + 4 * g;    // m-tile w+4
    const int eoD = (w + 6) * 16 + 4 * g;    // m-tile w+6

    // ---- el pipeline: 4 rotating raw quads, 2 exp quads ----
    f32x4 R0A, R0B, R0C, R0D, R1A, R1B, R1C, R1D;
    f32x4 R2A, R2B, R2C, R2D, R3A, R3B, R3C, R3D;
    f32x4 E0A, E0B, E0C, E0D, E1A, E1B, E1C, E1D;
    R0A = *(const f32x4*)(lsrc + eoA);          R0B = *(const f32x4*)(lsrc + eoB);
    R0C = *(const f32x4*)(lsrc + eoC);          R0D = *(const f32x4*)(lsrc + eoD);
    R1A = *(const f32x4*)(lsrc + NL + eoA);     R1B = *(const f32x4*)(lsrc + NL + eoB);
    R1C = *(const f32x4*)(lsrc + NL + eoC);     R1D = *(const f32x4*)(lsrc + NL + eoD);
    R2A = *(const f32x4*)(lsrc + 2*NL + eoA);   R2B = *(const f32x4*)(lsrc + 2*NL + eoB);
    R2C = *(const f32x4*)(lsrc + 2*NL + eoC);   R2D = *(const f32x4*)(lsrc + 2*NL + eoD);
    #pragma unroll
    for (int r = 0; r < 4; ++r) {
        E0A[r] = __expf(R0A[r]);  E0B[r] = __expf(R0B[r]);
        E0C[r] = __expf(R0C[r]);  E0D[r] = __expf(R0D[r]);
    }

    int cbi = 0;
    int t = 0;
    const int tmain = glen & ~3;
    for (; t < tmain; t += 4) {
        STEP(t + 0, false, false, E0, E1, R1, R3);
        STEP(t + 1, false, false, E1, E0, R2, R0);
        STEP(t + 2, true,  false, E0, E1, R3, R1);
        STEP(t + 3, false, true,  E1, E0, R0, R2);
    }
    if (t < glen) { STEP(t, false, false, E0, E1, R1, R3); ++t; }
    if (t < glen) { STEP(t, false, false, E1, E0, R2, R0); ++t; }
    if (t < glen) { STEP(t, true,  false, E0, E1, R3, R1); ++t; }

    // ---- epilogue (wave 0 holds all four groups: own P(kk0=0),Q(kk1=2),
    //      read X(kk2=1),Y(kk3=3)) ----
    if (w == 0) {
        float s = 0.f;
        const float* stopr = trans + STOP_IDX * NL + 4 * g;
        u32x4 gvk[4];
        gvk[0] = (u32x4){bwP0, bwP1, bwP2, bwP3};   // kk=0
        gvk[2] = (u32x4){bwQ0, bwQ1, bwQ2, bwQ3};   // kk=2
        gvk[1] = bvX;                               // kk=1
        gvk[3] = bvY;                               // kk=3
        #pragma unroll
        for (int kk = 0; kk < 4; ++kk) {
            f32x4 t0 = *(const f32x4*)(stopr + kk * 16);
            f32x4 t1 = *(const f32x4*)(stopr + (kk + 4) * 16);
            #pragma unroll
            for (int i = 0; i < 2; ++i) {
                const unsigned wd = gvk[kk][i];
                s += __uint_as_float(wd << 16)         * __expf(t0[2 * i]);
                s += __uint_as_float(wd & 0xFFFF0000u) * __expf(t0[2 * i + 1]);
            }
            #pragma unroll
            for (int i = 2; i < 4; ++i) {
                const unsigned wd = gvk[kk][i];
                s += __uint_as_float(wd << 16)         * __expf(t1[2 * (i - 2)]);
                s += __uint_as_float(wd & 0xFFFF0000u) * __expf(t1[2 * (i - 2) + 1]);
            }
        }
        s += __shfl_xor(s, 16);
        s += __shfl_xor(s, 32);
        if (g == 0)
            out[b0 + c] = (float)cbi * 0.69314718055994531f + __logf(s);
    }
}

extern "C" void kernel_launch(void* const* d_in, const int* in_sizes, int n_in,
                              void* d_out, int out_size, void* d_ws, size_t ws_size,
                              hipStream_t stream) {
    const float* logits = (const float*)d_in[0];
    const int*   lens   = (const int*)d_in[1];
    const float* trans  = (const float*)d_in[2];
    float*       outp   = (float*)d_out;
    crf_scan<<<NB / 16, 128, 0, stream>>>(logits, lens, trans, outp);
}